// Round 12
// baseline (118.329 us; speedup 1.0000x reference)
//
#include <hip/hip_runtime.h>

// HopfRNNCellTheta: T=64 < UNITS=1024 -> z[:,0] stays 0 -> A unused,
// y_t = 0.5*(B@x_t). Output = REAL part only, float32[64][1024][1024].
// out[t][n][u] = ReY[s][n], s = t+u-1023, if s>=0 else 0.
//
// r12 = r11 gemv (K-split, barrier-free, wave-private B in LDS, ping-pong
// xT reads) + WORK-STEALING fill: 8192 x 32KB chunks via atomic counter in
// d_ws (reset by K0); all 1024 blocks steal; gemv blocks join after their
// band write -> no static tail, full capacity post-gemv.

#define NDIM 1024
#define NCHUNK 8192            // 2^24 float4 words / 2^11 words per chunk

// ---- K0: xT[m][t] transpose + counter reset ----
__global__ __launch_bounds__(256) void transpose_x(
    const float* __restrict__ x_re, const float* __restrict__ x_im,
    float2* __restrict__ xT, int* __restrict__ counter) {
  __shared__ float s1[64][65];
  __shared__ float s2[64][65];
  const int tid = threadIdx.x;
  if (blockIdx.x == 0 && tid == 0) *counter = 0;   // visible to K1 (stream order)
  const int m0 = blockIdx.x * 64;
#pragma unroll
  for (int k = 0; k < 16; ++k) {           // coalesced reads
    const int s = tid + k * 256;
    const int tr = s >> 6, j = s & 63;
    s1[tr][j] = x_re[tr * NDIM + m0 + j];
    s2[tr][j] = x_im[tr * NDIM + m0 + j];
  }
  __syncthreads();
#pragma unroll
  for (int k = 0; k < 16; ++k) {           // coalesced writes, CF LDS reads
    const int s = tid + k * 256;
    const int ml = s >> 6, t = s & 63;
    xT[(m0 + ml) * 64 + t] = make_float2(s1[t][ml], s2[t][ml]);
  }
}

// ---- work-stealing zero-fill of all out-of-band words (r6 boundary logic) ----
__device__ __forceinline__ void fill_steal(float* __restrict__ out,
                                           int* __restrict__ counter,
                                           int tid, int* chsh) {
  float4* out4 = (float4*)out;
  const float4 z = make_float4(0.f, 0.f, 0.f, 0.f);
  if (tid == 0) chsh[0] = atomicAdd(counter, 1);
  __syncthreads();
  int cur = chsh[0];
  int buf = 0;
  while (cur < NCHUNK) {
    if (tid == 0) chsh[buf ^ 1] = atomicAdd(counter, 1);  // prefetch next id
    const int qb = cur << 11;
#pragma unroll
    for (int k = 0; k < 8; ++k) {
      const int q = qb + k * 256 + tid;
      const int t = q >> 18;
      const int u4 = q & 255;
      const int sb = t + 4 * u4 - 1023;    // s of word component 0
      if (sb <= -4) {                       // fully out of band (~97%)
        out4[q] = z;
      } else if (sb < 0) {                  // boundary word: mixed bytes
        float* p = out + ((long long)q << 2);
        p[0] = 0.f;
        if (sb + 1 < 0) p[1] = 0.f;
        if (sb + 2 < 0) p[2] = 0.f;         // sb+3 >= 0 always here
      }
    }
    __syncthreads();                        // publish chsh[buf^1]
    cur = chsh[buf ^ 1];
    buf ^= 1;
  }
}

// ---- K1: fused gemv + stealing fill ----
__global__ __launch_bounds__(256) void hopf_fused5(
    const float2* __restrict__ xT,
    const float* __restrict__ B_re, const float* __restrict__ B_im,
    float* __restrict__ out, int* __restrict__ counter) {
  __shared__ float bsR[4][4][256];   // [wave][row][m'] (wave-private)
  __shared__ float bsI[4][4][256];
  __shared__ float red[4][4][64];    // [k-wave][row][t]
  __shared__ int chsh[2];
  const int tid = threadIdx.x;

  if (blockIdx.x >= 256) {
    fill_steal(out, counter, tid, chsh);
    return;
  }

  // ---------- gemv: block rows nb..nb+3; wave w reduces m-quarter w ----------
  __builtin_amdgcn_s_setprio(1);
  const int t = tid & 63;
  const int w = tid >> 6;
  const int nb = blockIdx.x * 4;
  const int mbase = w << 8;

  // stage B[nb+r][mbase..mbase+256) into wave-private LDS (no barrier:
  // same-wave ds_write->ds_read ordered by compiler lgkmcnt)
#pragma unroll
  for (int r = 0; r < 4; ++r) {
    *(float4*)&bsR[w][r][t * 4] =
        *(const float4*)(B_re + (nb + r) * NDIM + mbase + t * 4);
    *(float4*)&bsI[w][r][t * 4] =
        *(const float4*)(B_im + (nb + r) * NDIM + mbase + t * 4);
  }

  float a1_0 = 0.f, a2_0 = 0.f, a1_1 = 0.f, a2_1 = 0.f;
  float a1_2 = 0.f, a2_2 = 0.f, a1_3 = 0.f, a2_3 = 0.f;
  const float2* xp = xT + (mbase << 6) + t;
  float2 xv[16], xn[16];

#define ROWFMA(R, BR, BI, X)                                            \
  do {                                                                  \
    a1_##R = fmaf(BR.x, X[0].x, a1_##R);                                \
    a2_##R = fmaf(BI.x, X[0].y, a2_##R);                                \
    a1_##R = fmaf(BR.y, X[1].x, a1_##R);                                \
    a2_##R = fmaf(BI.y, X[1].y, a2_##R);                                \
    a1_##R = fmaf(BR.z, X[2].x, a1_##R);                                \
    a2_##R = fmaf(BI.z, X[2].y, a2_##R);                                \
    a1_##R = fmaf(BR.w, X[3].x, a1_##R);                                \
    a2_##R = fmaf(BI.w, X[3].y, a2_##R);                                \
  } while (0)

#define COMP(X, MB)                                                     \
  do {                                                                  \
    _Pragma("unroll")                                                   \
    for (int q = 0; q < 4; ++q) {                                       \
      const float2* Xq = &X[q * 4];                                     \
      const float4 br0 = *(const float4*)&bsR[w][0][(MB) + q * 4];      \
      const float4 bi0 = *(const float4*)&bsI[w][0][(MB) + q * 4];      \
      ROWFMA(0, br0, bi0, Xq);                                          \
      const float4 br1 = *(const float4*)&bsR[w][1][(MB) + q * 4];      \
      const float4 bi1 = *(const float4*)&bsI[w][1][(MB) + q * 4];      \
      ROWFMA(1, br1, bi1, Xq);                                          \
      const float4 br2 = *(const float4*)&bsR[w][2][(MB) + q * 4];      \
      const float4 bi2 = *(const float4*)&bsI[w][2][(MB) + q * 4];      \
      ROWFMA(2, br2, bi2, Xq);                                          \
      const float4 br3 = *(const float4*)&bsR[w][3][(MB) + q * 4];      \
      const float4 bi3 = *(const float4*)&bsI[w][3][(MB) + q * 4];      \
      ROWFMA(3, br3, bi3, Xq);                                          \
    }                                                                   \
  } while (0)

#pragma unroll
  for (int j = 0; j < 16; ++j) xv[j] = xp[j * 64];   // chunk 0 in flight

#pragma unroll 1
  for (int m0 = 0; m0 < 256; m0 += 32) {
#pragma unroll
    for (int j = 0; j < 16; ++j) xn[j] = xp[(m0 + 16 + j) * 64];
    COMP(xv, m0);
    if (m0 + 32 < 256) {
#pragma unroll
      for (int j = 0; j < 16; ++j) xv[j] = xp[(m0 + 32 + j) * 64];
    }
    COMP(xn, m0 + 16);
  }

  // ---------- cross-wave K-reduce ----------
  red[w][0][t] = a1_0 - a2_0;
  red[w][1][t] = a1_1 - a2_1;
  red[w][2][t] = a1_2 - a2_2;
  red[w][3][t] = a1_3 - a2_3;
  __syncthreads();
  const float yv =
      0.5f * (red[0][w][t] + red[1][w][t] + red[2][w][t] + red[3][w][t]);

  // ---------- band write: wave-uniform tt -> coalesced bursts ----------
  const long long rowoff = (long long)(nb + w) << 10;
  for (int tt = 0; tt < 64; ++tt) {
    if (t <= tt) {
      out[((long long)tt << 20) + rowoff + (1023 - tt) + t] = yv;
    }
  }

  // ---------- join the fill ----------
  __builtin_amdgcn_s_setprio(0);
  fill_steal(out, counter, tid, chsh);
}

// ---- fallback (round-6 fused, known-passing; used only if ws too small) ----
__global__ __launch_bounds__(256) void hopf_fused_fb(
    const float* __restrict__ x_re, const float* __restrict__ x_im,
    const float* __restrict__ B_re, const float* __restrict__ B_im,
    float* __restrict__ out) {
  __shared__ float s1[64][65];
  __shared__ float s2[64][65];
  const int tid = threadIdx.x;
  if (blockIdx.x >= 256) {
    float4* out4 = (float4*)out;
    const float4 z = make_float4(0.f, 0.f, 0.f, 0.f);
    const int stride = 768 * 256;
    for (int q = (int)(blockIdx.x - 256) * 256 + tid; q < (1 << 24);
         q += stride) {
      const int t = q >> 18;
      const int u4 = q & 255;
      const int sb = t + 4 * u4 - 1023;
      if (sb <= -4) {
        out4[q] = z;
      } else if (sb < 0) {
        float* p = out + ((long long)q << 2);
        p[0] = 0.f;
        if (sb + 1 < 0) p[1] = 0.f;
        if (sb + 2 < 0) p[2] = 0.f;
      }
    }
    return;
  }
  const int t = tid & 63;
  const int ng = tid >> 6;
  const int n = blockIdx.x * 4 + ng;
  const float* p1 = B_re + n * NDIM;
  const float* p2 = B_im + n * NDIM;
  float a1 = 0.f, a2 = 0.f;
  for (int m0 = 0; m0 < NDIM; m0 += 64) {
    __syncthreads();
#pragma unroll
    for (int k = 0; k < 16; ++k) {
      const int s = tid + k * 256;
      const int tr2 = s >> 6, j = s & 63;
      s1[tr2][j] = x_re[tr2 * NDIM + m0 + j];
      s2[tr2][j] = x_im[tr2 * NDIM + m0 + j];
    }
    __syncthreads();
#pragma unroll 16
    for (int mm = 0; mm < 64; ++mm) {
      a1 = fmaf(p1[m0 + mm], s1[t][mm], a1);
      a2 = fmaf(p2[m0 + mm], s2[t][mm], a2);
    }
  }
  const float yv = 0.5f * (a1 - a2);
  const long long rowoff = (long long)(n << 10);
  for (int tt = 0; tt < 64; ++tt) {
    if (t <= tt) {
      out[((long long)tt << 20) + rowoff + (1023 - tt) + t] = yv;
    }
  }
}

extern "C" void kernel_launch(void* const* d_in, const int* in_sizes, int n_in,
                              void* d_out, int out_size, void* d_ws, size_t ws_size,
                              hipStream_t stream) {
  (void)in_sizes; (void)n_in; (void)out_size;
  const float* x_re = (const float*)d_in[0];
  const float* x_im = (const float*)d_in[1];
  const float* B_re = (const float*)d_in[4];
  const float* B_im = (const float*)d_in[5];
  float* out = (float*)d_out;

  const size_t xt_bytes = (size_t)NDIM * 64 * sizeof(float2);  // 512 KB
  if (ws_size >= xt_bytes + 64) {
    float2* xT = (float2*)d_ws;
    int* counter = (int*)((char*)d_ws + xt_bytes);
    transpose_x<<<16, 256, 0, stream>>>(x_re, x_im, xT, counter);
    hopf_fused5<<<1024, 256, 0, stream>>>(xT, B_re, B_im, out, counter);
  } else {
    hopf_fused_fb<<<1024, 256, 0, stream>>>(x_re, x_im, B_re, B_im, out);
  }
}

// Round 13
// 49.502 us; speedup vs baseline: 2.3904x; 2.3904x over previous
//
#include <hip/hip_runtime.h>

// HopfRNNCellTheta: T=64 < UNITS=1024 -> z[:,0] stays 0 -> A unused,
// y_t = 0.5*(B@x_t). Output = REAL part only, float32[64][1024][1024].
// out[t][n][u] = ReY[s][n], s = t+u-1023, if s>=0 else 0.
//
// r13 = r11 gemv (K-split, barrier-free, wave-private B in LDS, ping-pong
// xT reads; 54.3us proven) + ROW-STRUCTURED fill: one wave per (t,n) row,
// per-row math hoisted (Z=(1023-t)>>2 zero words, k=(1023-t)&3 partial
// comps), inner loop = pure unconditional float4 stores (~1.3 instr/word vs
// ~10 in r11 -> fill moves from VALU-issue-bound 3.9TB/s to BW-bound).
// r12's atomic work-stealing reverted (cross-XCD atomics serialized, +64us).

#define NDIM 1024

// ---- K0: xT[m][t] = (x_re[t][m], x_im[t][m]); 16 blocks, LDS transpose ----
__global__ __launch_bounds__(256) void transpose_x(
    const float* __restrict__ x_re, const float* __restrict__ x_im,
    float2* __restrict__ xT) {
  __shared__ float s1[64][65];
  __shared__ float s2[64][65];
  const int tid = threadIdx.x;
  const int m0 = blockIdx.x * 64;
#pragma unroll
  for (int k = 0; k < 16; ++k) {           // coalesced reads
    const int s = tid + k * 256;
    const int tr = s >> 6, j = s & 63;
    s1[tr][j] = x_re[tr * NDIM + m0 + j];
    s2[tr][j] = x_im[tr * NDIM + m0 + j];
  }
  __syncthreads();
#pragma unroll
  for (int k = 0; k < 16; ++k) {           // coalesced writes, CF LDS reads
    const int s = tid + k * 256;
    const int ml = s >> 6, t = s & 63;
    xT[(m0 + ml) * 64 + t] = make_float2(s1[t][ml], s2[t][ml]);
  }
}

// ---- K1: fused gemv + row-structured zero-fill ----
__global__ __launch_bounds__(256) void hopf_fused6(
    const float2* __restrict__ xT,
    const float* __restrict__ B_re, const float* __restrict__ B_im,
    float* __restrict__ out) {
  __shared__ float bsR[4][4][256];   // [wave][row][m'] (wave-private)
  __shared__ float bsI[4][4][256];
  __shared__ float red[4][4][64];    // [k-wave][row][t]
  const int tid = threadIdx.x;

  if (blockIdx.x >= 256) {
    // ---------- row-structured fill: one wave per (t,n) row ----------
    // Row (t,n): words [0,Z) fully zero, word Z components [0,k) zero,
    // everything else is band (gemv writes). Z=(1023-t)>>2, k=(1023-t)&3.
    const int lane = tid & 63;
    const int gw = (int)(blockIdx.x - 256) * 4 + (tid >> 6);  // 0..3071
    const float4 z = make_float4(0.f, 0.f, 0.f, 0.f);
    for (int r = gw; r < 64 * 1024; r += 768 * 4) {
      const int t = r >> 10;
      const int n = r & 1023;
      const int rem = 1023 - t;
      const int Z = rem >> 2;              // 240..255
      const int k = rem & 3;
      float4* rp = (float4*)out + ((long long)t << 18) + (n << 8);
      rp[lane] = z;                        // lanes 0..63   (< 240 always)
      rp[lane + 64] = z;                   // 64..127
      rp[lane + 128] = z;                  // 128..191
      if (lane + 192 < Z) rp[lane + 192] = z;
      if (lane < k) ((float*)(rp + Z))[lane] = 0.f;   // partial word
    }
    return;
  }

  // ---------- gemv: block rows nb..nb+3; wave w reduces m-quarter w ----------
  __builtin_amdgcn_s_setprio(1);
  const int t = tid & 63;
  const int w = tid >> 6;
  const int nb = blockIdx.x * 4;
  const int mbase = w << 8;

  // stage B[nb+r][mbase..mbase+256) into wave-private LDS (no barrier:
  // same-wave ds_write->ds_read ordered by compiler lgkmcnt)
#pragma unroll
  for (int r = 0; r < 4; ++r) {
    *(float4*)&bsR[w][r][t * 4] =
        *(const float4*)(B_re + (nb + r) * NDIM + mbase + t * 4);
    *(float4*)&bsI[w][r][t * 4] =
        *(const float4*)(B_im + (nb + r) * NDIM + mbase + t * 4);
  }

  float a1_0 = 0.f, a2_0 = 0.f, a1_1 = 0.f, a2_1 = 0.f;
  float a1_2 = 0.f, a2_2 = 0.f, a1_3 = 0.f, a2_3 = 0.f;
  const float2* xp = xT + (mbase << 6) + t;
  float2 xv[16], xn[16];

#define ROWFMA(R, BR, BI, X)                                            \
  do {                                                                  \
    a1_##R = fmaf(BR.x, X[0].x, a1_##R);                                \
    a2_##R = fmaf(BI.x, X[0].y, a2_##R);                                \
    a1_##R = fmaf(BR.y, X[1].x, a1_##R);                                \
    a2_##R = fmaf(BI.y, X[1].y, a2_##R);                                \
    a1_##R = fmaf(BR.z, X[2].x, a1_##R);                                \
    a2_##R = fmaf(BI.z, X[2].y, a2_##R);                                \
    a1_##R = fmaf(BR.w, X[3].x, a1_##R);                                \
    a2_##R = fmaf(BI.w, X[3].y, a2_##R);                                \
  } while (0)

#define COMP(X, MB)                                                     \
  do {                                                                  \
    _Pragma("unroll")                                                   \
    for (int q = 0; q < 4; ++q) {                                       \
      const float2* Xq = &X[q * 4];                                     \
      const float4 br0 = *(const float4*)&bsR[w][0][(MB) + q * 4];      \
      const float4 bi0 = *(const float4*)&bsI[w][0][(MB) + q * 4];      \
      ROWFMA(0, br0, bi0, Xq);                                          \
      const float4 br1 = *(const float4*)&bsR[w][1][(MB) + q * 4];      \
      const float4 bi1 = *(const float4*)&bsI[w][1][(MB) + q * 4];      \
      ROWFMA(1, br1, bi1, Xq);                                          \
      const float4 br2 = *(const float4*)&bsR[w][2][(MB) + q * 4];      \
      const float4 bi2 = *(const float4*)&bsI[w][2][(MB) + q * 4];      \
      ROWFMA(2, br2, bi2, Xq);                                          \
      const float4 br3 = *(const float4*)&bsR[w][3][(MB) + q * 4];      \
      const float4 bi3 = *(const float4*)&bsI[w][3][(MB) + q * 4];      \
      ROWFMA(3, br3, bi3, Xq);                                          \
    }                                                                   \
  } while (0)

#pragma unroll
  for (int j = 0; j < 16; ++j) xv[j] = xp[j * 64];   // chunk 0 in flight

#pragma unroll 1
  for (int m0 = 0; m0 < 256; m0 += 32) {
#pragma unroll
    for (int j = 0; j < 16; ++j) xn[j] = xp[(m0 + 16 + j) * 64];
    COMP(xv, m0);
    if (m0 + 32 < 256) {
#pragma unroll
      for (int j = 0; j < 16; ++j) xv[j] = xp[(m0 + 32 + j) * 64];
    }
    COMP(xn, m0 + 16);
  }

  // ---------- cross-wave K-reduce ----------
  red[w][0][t] = a1_0 - a2_0;
  red[w][1][t] = a1_1 - a2_1;
  red[w][2][t] = a1_2 - a2_2;
  red[w][3][t] = a1_3 - a2_3;
  __syncthreads();
  const float yv =
      0.5f * (red[0][w][t] + red[1][w][t] + red[2][w][t] + red[3][w][t]);

  // ---------- band write: wave-uniform tt -> coalesced bursts ----------
  const long long rowoff = (long long)(nb + w) << 10;
  for (int tt = 0; tt < 64; ++tt) {
    if (t <= tt) {
      out[((long long)tt << 20) + rowoff + (1023 - tt) + t] = yv;
    }
  }
}

// ---- fallback (round-6 fused, known-passing; used only if ws too small) ----
__global__ __launch_bounds__(256) void hopf_fused_fb(
    const float* __restrict__ x_re, const float* __restrict__ x_im,
    const float* __restrict__ B_re, const float* __restrict__ B_im,
    float* __restrict__ out) {
  __shared__ float s1[64][65];
  __shared__ float s2[64][65];
  const int tid = threadIdx.x;
  if (blockIdx.x >= 256) {
    float4* out4 = (float4*)out;
    const float4 z = make_float4(0.f, 0.f, 0.f, 0.f);
    const int stride = 768 * 256;
    for (int q = (int)(blockIdx.x - 256) * 256 + tid; q < (1 << 24);
         q += stride) {
      const int t = q >> 18;
      const int u4 = q & 255;
      const int sb = t + 4 * u4 - 1023;
      if (sb <= -4) {
        out4[q] = z;
      } else if (sb < 0) {
        float* p = out + ((long long)q << 2);
        p[0] = 0.f;
        if (sb + 1 < 0) p[1] = 0.f;
        if (sb + 2 < 0) p[2] = 0.f;
      }
    }
    return;
  }
  const int t = tid & 63;
  const int ng = tid >> 6;
  const int n = blockIdx.x * 4 + ng;
  const float* p1 = B_re + n * NDIM;
  const float* p2 = B_im + n * NDIM;
  float a1 = 0.f, a2 = 0.f;
  for (int m0 = 0; m0 < NDIM; m0 += 64) {
    __syncthreads();
#pragma unroll
    for (int k = 0; k < 16; ++k) {
      const int s = tid + k * 256;
      const int tr2 = s >> 6, j = s & 63;
      s1[tr2][j] = x_re[tr2 * NDIM + m0 + j];
      s2[tr2][j] = x_im[tr2 * NDIM + m0 + j];
    }
    __syncthreads();
#pragma unroll 16
    for (int mm = 0; mm < 64; ++mm) {
      a1 = fmaf(p1[m0 + mm], s1[t][mm], a1);
      a2 = fmaf(p2[m0 + mm], s2[t][mm], a2);
    }
  }
  const float yv = 0.5f * (a1 - a2);
  const long long rowoff = (long long)(n << 10);
  for (int tt = 0; tt < 64; ++tt) {
    if (t <= tt) {
      out[((long long)tt << 20) + rowoff + (1023 - tt) + t] = yv;
    }
  }
}

extern "C" void kernel_launch(void* const* d_in, const int* in_sizes, int n_in,
                              void* d_out, int out_size, void* d_ws, size_t ws_size,
                              hipStream_t stream) {
  (void)in_sizes; (void)n_in; (void)out_size;
  const float* x_re = (const float*)d_in[0];
  const float* x_im = (const float*)d_in[1];
  const float* B_re = (const float*)d_in[4];
  const float* B_im = (const float*)d_in[5];
  float* out = (float*)d_out;

  if (ws_size >= (size_t)(NDIM * 64 * sizeof(float2))) {
    float2* xT = (float2*)d_ws;   // [1024 m][64 t], 512 KB
    transpose_x<<<16, 256, 0, stream>>>(x_re, x_im, xT);
    hopf_fused6<<<1024, 256, 0, stream>>>(xT, B_re, B_im, out);
  } else {
    hopf_fused_fb<<<1024, 256, 0, stream>>>(x_re, x_im, B_re, B_im, out);
  }
}

// Round 14
// 49.171 us; speedup vs baseline: 2.4065x; 1.0067x over previous
//
#include <hip/hip_runtime.h>

// HopfRNNCellTheta: T=64 < UNITS=1024 -> z[:,0] stays 0 -> A unused,
// y_t = 0.5*(B@x_t). Output = REAL part only, float32[64][1024][1024].
// out[t][n][u] = ReY[s][n], s = t+u-1023, if s>=0 else 0.
//
// r14 = r13 (row-structured fill ~1.3 instr/word, r11 gemv core) +
// zero-idle-BW scheduling:
//   K0: 16 transpose blocks + 240 fill blocks (rows 59776..65535) -> the
//       transpose rides along with useful write BW instead of a dead 2us.
//   K1: 256 gemv blocks (band write, then static fill share rows
//       52224..59775) + 768 fill blocks (rows 0..52223, 17/wave).
// Row partition exact & disjoint from band cells; no atomics (r12 lesson).

#define NDIM 1024

// zero-prefix of row r = (t,n): words [0,Z) zero, word Z comps [0,k) zero.
// Z = (1023-t)>>2 in [240,256), k = (1023-t)&3. Band cells untouched.
__device__ __forceinline__ void fill_rows(float* __restrict__ out, int rstart,
                                          int rcount, int rlimit, int lane) {
  const float4 z = make_float4(0.f, 0.f, 0.f, 0.f);
  int rend = rstart + rcount;
  if (rend > rlimit) rend = rlimit;
  for (int r = rstart; r < rend; ++r) {
    const int t = r >> 10;
    const int n = r & 1023;
    const int rem = 1023 - t;
    const int Z = rem >> 2;
    const int k = rem & 3;
    float4* rp = (float4*)out + ((long long)t << 18) + (n << 8);
    rp[lane] = z;                          // lanes 0..63  (< 240 <= Z)
    rp[lane + 64] = z;
    rp[lane + 128] = z;
    if (lane + 192 < Z) rp[lane + 192] = z;
    if (lane < k) ((float*)(rp + Z))[lane] = 0.f;
  }
}

// ---- K0: 16 transpose blocks + 240 fill blocks ----
__global__ __launch_bounds__(256) void k0_transpose_fill(
    const float* __restrict__ x_re, const float* __restrict__ x_im,
    float2* __restrict__ xT, float* __restrict__ out) {
  __shared__ float s1[64][65];
  __shared__ float s2[64][65];
  const int tid = threadIdx.x;
  if (blockIdx.x >= 16) {
    const int kw = (int)(blockIdx.x - 16) * 4 + (tid >> 6);  // 0..959
    fill_rows(out, 59776 + kw * 6, 6, 65536, tid & 63);
    return;
  }
  const int m0 = blockIdx.x * 64;
#pragma unroll
  for (int k = 0; k < 16; ++k) {           // coalesced reads
    const int s = tid + k * 256;
    const int tr = s >> 6, j = s & 63;
    s1[tr][j] = x_re[tr * NDIM + m0 + j];
    s2[tr][j] = x_im[tr * NDIM + m0 + j];
  }
  __syncthreads();
#pragma unroll
  for (int k = 0; k < 16; ++k) {           // coalesced writes, CF LDS reads
    const int s = tid + k * 256;
    const int ml = s >> 6, t = s & 63;
    xT[(m0 + ml) * 64 + t] = make_float2(s1[t][ml], s2[t][ml]);
  }
}

// ---- K1: fused gemv + row-structured zero-fill ----
__global__ __launch_bounds__(256) void hopf_fused7(
    const float2* __restrict__ xT,
    const float* __restrict__ B_re, const float* __restrict__ B_im,
    float* __restrict__ out) {
  __shared__ float bsR[4][4][256];   // [wave][row][m'] (wave-private)
  __shared__ float bsI[4][4][256];
  __shared__ float red[4][4][64];    // [k-wave][row][t]
  const int tid = threadIdx.x;
  const int t = tid & 63;
  const int w = tid >> 6;

  if (blockIdx.x >= 256) {
    const int gfw = (int)(blockIdx.x - 256) * 4 + w;   // 0..3071
    fill_rows(out, gfw * 17, 17, 52224, t);
    return;
  }

  // ---------- gemv: block rows nb..nb+3; wave w reduces m-quarter w ----------
  __builtin_amdgcn_s_setprio(1);
  const int nb = blockIdx.x * 4;
  const int mbase = w << 8;

  // stage B[nb+r][mbase..mbase+256) into wave-private LDS (no barrier:
  // same-wave ds_write->ds_read ordered by compiler lgkmcnt)
#pragma unroll
  for (int r = 0; r < 4; ++r) {
    *(float4*)&bsR[w][r][t * 4] =
        *(const float4*)(B_re + (nb + r) * NDIM + mbase + t * 4);
    *(float4*)&bsI[w][r][t * 4] =
        *(const float4*)(B_im + (nb + r) * NDIM + mbase + t * 4);
  }

  float a1_0 = 0.f, a2_0 = 0.f, a1_1 = 0.f, a2_1 = 0.f;
  float a1_2 = 0.f, a2_2 = 0.f, a1_3 = 0.f, a2_3 = 0.f;
  const float2* xp = xT + (mbase << 6) + t;
  float2 xv[16], xn[16];

#define ROWFMA(R, BR, BI, X)                                            \
  do {                                                                  \
    a1_##R = fmaf(BR.x, X[0].x, a1_##R);                                \
    a2_##R = fmaf(BI.x, X[0].y, a2_##R);                                \
    a1_##R = fmaf(BR.y, X[1].x, a1_##R);                                \
    a2_##R = fmaf(BI.y, X[1].y, a2_##R);                                \
    a1_##R = fmaf(BR.z, X[2].x, a1_##R);                                \
    a2_##R = fmaf(BI.z, X[2].y, a2_##R);                                \
    a1_##R = fmaf(BR.w, X[3].x, a1_##R);                                \
    a2_##R = fmaf(BI.w, X[3].y, a2_##R);                                \
  } while (0)

#define COMP(X, MB)                                                     \
  do {                                                                  \
    _Pragma("unroll")                                                   \
    for (int q = 0; q < 4; ++q) {                                       \
      const float2* Xq = &X[q * 4];                                     \
      const float4 br0 = *(const float4*)&bsR[w][0][(MB) + q * 4];      \
      const float4 bi0 = *(const float4*)&bsI[w][0][(MB) + q * 4];      \
      ROWFMA(0, br0, bi0, Xq);                                          \
      const float4 br1 = *(const float4*)&bsR[w][1][(MB) + q * 4];      \
      const float4 bi1 = *(const float4*)&bsI[w][1][(MB) + q * 4];      \
      ROWFMA(1, br1, bi1, Xq);                                          \
      const float4 br2 = *(const float4*)&bsR[w][2][(MB) + q * 4];      \
      const float4 bi2 = *(const float4*)&bsI[w][2][(MB) + q * 4];      \
      ROWFMA(2, br2, bi2, Xq);                                          \
      const float4 br3 = *(const float4*)&bsR[w][3][(MB) + q * 4];      \
      const float4 bi3 = *(const float4*)&bsI[w][3][(MB) + q * 4];      \
      ROWFMA(3, br3, bi3, Xq);                                          \
    }                                                                   \
  } while (0)

#pragma unroll
  for (int j = 0; j < 16; ++j) xv[j] = xp[j * 64];   // chunk 0 in flight

#pragma unroll 1
  for (int m0 = 0; m0 < 256; m0 += 32) {
#pragma unroll
    for (int j = 0; j < 16; ++j) xn[j] = xp[(m0 + 16 + j) * 64];
    COMP(xv, m0);
    if (m0 + 32 < 256) {
#pragma unroll
      for (int j = 0; j < 16; ++j) xv[j] = xp[(m0 + 32 + j) * 64];
    }
    COMP(xn, m0 + 16);
  }

  // ---------- cross-wave K-reduce ----------
  red[w][0][t] = a1_0 - a2_0;
  red[w][1][t] = a1_1 - a2_1;
  red[w][2][t] = a1_2 - a2_2;
  red[w][3][t] = a1_3 - a2_3;
  __syncthreads();
  const float yv =
      0.5f * (red[0][w][t] + red[1][w][t] + red[2][w][t] + red[3][w][t]);

  // ---------- band write: wave-uniform tt -> coalesced bursts ----------
  const long long rowoff = (long long)(nb + w) << 10;
  for (int tt = 0; tt < 64; ++tt) {
    if (t <= tt) {
      out[((long long)tt << 20) + rowoff + (1023 - tt) + t] = yv;
    }
  }

  // ---------- static post-gemv fill share ----------
  __builtin_amdgcn_s_setprio(0);
  const int gid = blockIdx.x * 4 + w;      // 0..1023
  fill_rows(out, 52224 + gid * 8, 8, 59776, t);
}

// ---- fallback (round-6 fused, known-passing; used only if ws too small) ----
__global__ __launch_bounds__(256) void hopf_fused_fb(
    const float* __restrict__ x_re, const float* __restrict__ x_im,
    const float* __restrict__ B_re, const float* __restrict__ B_im,
    float* __restrict__ out) {
  __shared__ float s1[64][65];
  __shared__ float s2[64][65];
  const int tid = threadIdx.x;
  if (blockIdx.x >= 256) {
    float4* out4 = (float4*)out;
    const float4 z = make_float4(0.f, 0.f, 0.f, 0.f);
    const int stride = 768 * 256;
    for (int q = (int)(blockIdx.x - 256) * 256 + tid; q < (1 << 24);
         q += stride) {
      const int t = q >> 18;
      const int u4 = q & 255;
      const int sb = t + 4 * u4 - 1023;
      if (sb <= -4) {
        out4[q] = z;
      } else if (sb < 0) {
        float* p = out + ((long long)q << 2);
        p[0] = 0.f;
        if (sb + 1 < 0) p[1] = 0.f;
        if (sb + 2 < 0) p[2] = 0.f;
      }
    }
    return;
  }
  const int t = tid & 63;
  const int ng = tid >> 6;
  const int n = blockIdx.x * 4 + ng;
  const float* p1 = B_re + n * NDIM;
  const float* p2 = B_im + n * NDIM;
  float a1 = 0.f, a2 = 0.f;
  for (int m0 = 0; m0 < NDIM; m0 += 64) {
    __syncthreads();
#pragma unroll
    for (int k = 0; k < 16; ++k) {
      const int s = tid + k * 256;
      const int tr2 = s >> 6, j = s & 63;
      s1[tr2][j] = x_re[tr2 * NDIM + m0 + j];
      s2[tr2][j] = x_im[tr2 * NDIM + m0 + j];
    }
    __syncthreads();
#pragma unroll 16
    for (int mm = 0; mm < 64; ++mm) {
      a1 = fmaf(p1[m0 + mm], s1[t][mm], a1);
      a2 = fmaf(p2[m0 + mm], s2[t][mm], a2);
    }
  }
  const float yv = 0.5f * (a1 - a2);
  const long long rowoff = (long long)(n << 10);
  for (int tt = 0; tt < 64; ++tt) {
    if (t <= tt) {
      out[((long long)tt << 20) + rowoff + (1023 - tt) + t] = yv;
    }
  }
}

extern "C" void kernel_launch(void* const* d_in, const int* in_sizes, int n_in,
                              void* d_out, int out_size, void* d_ws, size_t ws_size,
                              hipStream_t stream) {
  (void)in_sizes; (void)n_in; (void)out_size;
  const float* x_re = (const float*)d_in[0];
  const float* x_im = (const float*)d_in[1];
  const float* B_re = (const float*)d_in[4];
  const float* B_im = (const float*)d_in[5];
  float* out = (float*)d_out;

  if (ws_size >= (size_t)(NDIM * 64 * sizeof(float2))) {
    float2* xT = (float2*)d_ws;   // [1024 m][64 t], 512 KB
    k0_transpose_fill<<<256, 256, 0, stream>>>(x_re, x_im, xT, out);
    hopf_fused7<<<1024, 256, 0, stream>>>(xT, B_re, B_im, out);
  } else {
    hopf_fused_fb<<<1024, 256, 0, stream>>>(x_re, x_im, B_re, B_im, out);
  }
}

// Round 15
// 45.225 us; speedup vs baseline: 2.6165x; 1.0873x over previous
//
#include <hip/hip_runtime.h>

// HopfRNNCellTheta: T=64 < UNITS=1024 -> z[:,0] stays 0 -> A unused,
// y_t = 0.5*(B@x_t). Output = REAL part only, float32[64][1024][1024].
// out[t][n][u] = ReY[s][n], s = t+u-1023, if s>=0 else 0.
//
// r15 = r14 + PACKED-BF16 xT: every gemv block re-reads all of xT, so xT
// traffic = 256 blocks x sizeof(xT). At f32x2 that was 128 MB of L2 reads in
// the ~5us gemv phase (~3.2 TB/s/XCD demand vs ~4.3 available) -> fill
// writes starved behind gemv reads. bf16-pair packing (one u32 per (m,t))
// halves it to 64 MB and halves load instructions. Unpack = 2 VALU/m.
// Error: +~4e-3 absmax (bf16 x), total ~0.01 << 0.067 threshold.

#define NDIM 1024

__device__ __forceinline__ unsigned bf16_rtne(float f) {
  unsigned u = __float_as_uint(f);
  return (u + 0x7FFFu + ((u >> 16) & 1u)) >> 16;   // round-to-nearest-even
}

// zero-prefix of row r = (t,n): words [0,Z) zero, word Z comps [0,k) zero.
// Z = (1023-t)>>2 in [240,256), k = (1023-t)&3. Band cells untouched.
__device__ __forceinline__ void fill_rows(float* __restrict__ out, int rstart,
                                          int rcount, int rlimit, int lane) {
  const float4 z = make_float4(0.f, 0.f, 0.f, 0.f);
  int rend = rstart + rcount;
  if (rend > rlimit) rend = rlimit;
  for (int r = rstart; r < rend; ++r) {
    const int t = r >> 10;
    const int n = r & 1023;
    const int rem = 1023 - t;
    const int Z = rem >> 2;
    const int k = rem & 3;
    float4* rp = (float4*)out + ((long long)t << 18) + (n << 8);
    rp[lane] = z;                          // lanes 0..63  (< 240 <= Z)
    rp[lane + 64] = z;
    rp[lane + 128] = z;
    if (lane + 192 < Z) rp[lane + 192] = z;
    if (lane < k) ((float*)(rp + Z))[lane] = 0.f;
  }
}

// ---- K0: 16 transpose+pack blocks + 240 fill blocks ----
__global__ __launch_bounds__(256) void k0_transpose_fill(
    const float* __restrict__ x_re, const float* __restrict__ x_im,
    unsigned* __restrict__ xTb, float* __restrict__ out) {
  __shared__ float s1[64][65];
  __shared__ float s2[64][65];
  const int tid = threadIdx.x;
  if (blockIdx.x >= 16) {
    const int kw = (int)(blockIdx.x - 16) * 4 + (tid >> 6);  // 0..959
    fill_rows(out, 59776 + kw * 6, 6, 65536, tid & 63);
    return;
  }
  const int m0 = blockIdx.x * 64;
#pragma unroll
  for (int k = 0; k < 16; ++k) {           // coalesced reads
    const int s = tid + k * 256;
    const int tr = s >> 6, j = s & 63;
    s1[tr][j] = x_re[tr * NDIM + m0 + j];
    s2[tr][j] = x_im[tr * NDIM + m0 + j];
  }
  __syncthreads();
#pragma unroll
  for (int k = 0; k < 16; ++k) {           // coalesced writes, CF LDS reads
    const int s = tid + k * 256;
    const int ml = s >> 6, t = s & 63;
    // low16 = bf16(re), high16 = bf16(im)
    xTb[(m0 + ml) * 64 + t] =
        bf16_rtne(s1[t][ml]) | (bf16_rtne(s2[t][ml]) << 16);
  }
}

// ---- K1: fused gemv + row-structured zero-fill ----
__global__ __launch_bounds__(256) void hopf_fused8(
    const unsigned* __restrict__ xTb,
    const float* __restrict__ B_re, const float* __restrict__ B_im,
    float* __restrict__ out) {
  __shared__ float bsR[4][4][256];   // [wave][row][m'] (wave-private)
  __shared__ float bsI[4][4][256];
  __shared__ float red[4][4][64];    // [k-wave][row][t]
  const int tid = threadIdx.x;
  const int t = tid & 63;
  const int w = tid >> 6;

  if (blockIdx.x >= 256) {
    const int gfw = (int)(blockIdx.x - 256) * 4 + w;   // 0..3071
    fill_rows(out, gfw * 17, 17, 52224, t);
    return;
  }

  // ---------- gemv: block rows nb..nb+3; wave w reduces m-quarter w ----------
  __builtin_amdgcn_s_setprio(1);
  const int nb = blockIdx.x * 4;
  const int mbase = w << 8;

  // stage B[nb+r][mbase..mbase+256) into wave-private LDS (no barrier:
  // same-wave ds_write->ds_read ordered by compiler lgkmcnt)
#pragma unroll
  for (int r = 0; r < 4; ++r) {
    *(float4*)&bsR[w][r][t * 4] =
        *(const float4*)(B_re + (nb + r) * NDIM + mbase + t * 4);
    *(float4*)&bsI[w][r][t * 4] =
        *(const float4*)(B_im + (nb + r) * NDIM + mbase + t * 4);
  }

  float a1_0 = 0.f, a2_0 = 0.f, a1_1 = 0.f, a2_1 = 0.f;
  float a1_2 = 0.f, a2_2 = 0.f, a1_3 = 0.f, a2_3 = 0.f;
  const unsigned* xp = xTb + (mbase << 6) + t;
  unsigned xv[16], xn[16];

#define ROWFMA(R, BR, BI)                                               \
  do {                                                                  \
    a1_##R = fmaf(BR.x, xr0, a1_##R);                                   \
    a2_##R = fmaf(BI.x, xi0, a2_##R);                                   \
    a1_##R = fmaf(BR.y, xr1, a1_##R);                                   \
    a2_##R = fmaf(BI.y, xi1, a2_##R);                                   \
    a1_##R = fmaf(BR.z, xr2, a1_##R);                                   \
    a2_##R = fmaf(BI.z, xi2, a2_##R);                                   \
    a1_##R = fmaf(BR.w, xr3, a1_##R);                                   \
    a2_##R = fmaf(BI.w, xi3, a2_##R);                                   \
  } while (0)

#define COMP(X, MB)                                                     \
  do {                                                                  \
    _Pragma("unroll")                                                   \
    for (int q = 0; q < 4; ++q) {                                       \
      const unsigned w0 = X[q * 4 + 0], w1 = X[q * 4 + 1];              \
      const unsigned w2 = X[q * 4 + 2], w3 = X[q * 4 + 3];              \
      const float xr0 = __uint_as_float(w0 << 16);                      \
      const float xi0 = __uint_as_float(w0 & 0xFFFF0000u);              \
      const float xr1 = __uint_as_float(w1 << 16);                      \
      const float xi1 = __uint_as_float(w1 & 0xFFFF0000u);              \
      const float xr2 = __uint_as_float(w2 << 16);                      \
      const float xi2 = __uint_as_float(w2 & 0xFFFF0000u);              \
      const float xr3 = __uint_as_float(w3 << 16);                      \
      const float xi3 = __uint_as_float(w3 & 0xFFFF0000u);              \
      const float4 br0 = *(const float4*)&bsR[w][0][(MB) + q * 4];      \
      const float4 bi0 = *(const float4*)&bsI[w][0][(MB) + q * 4];      \
      ROWFMA(0, br0, bi0);                                              \
      const float4 br1 = *(const float4*)&bsR[w][1][(MB) + q * 4];      \
      const float4 bi1 = *(const float4*)&bsI[w][1][(MB) + q * 4];      \
      ROWFMA(1, br1, bi1);                                              \
      const float4 br2 = *(const float4*)&bsR[w][2][(MB) + q * 4];      \
      const float4 bi2 = *(const float4*)&bsI[w][2][(MB) + q * 4];      \
      ROWFMA(2, br2, bi2);                                              \
      const float4 br3 = *(const float4*)&bsR[w][3][(MB) + q * 4];      \
      const float4 bi3 = *(const float4*)&bsI[w][3][(MB) + q * 4];      \
      ROWFMA(3, br3, bi3);                                              \
    }                                                                   \
  } while (0)

#pragma unroll
  for (int j = 0; j < 16; ++j) xv[j] = xp[j * 64];   // chunk 0 in flight

#pragma unroll 1
  for (int m0 = 0; m0 < 256; m0 += 32) {
#pragma unroll
    for (int j = 0; j < 16; ++j) xn[j] = xp[(m0 + 16 + j) * 64];
    COMP(xv, m0);
    if (m0 + 32 < 256) {
#pragma unroll
      for (int j = 0; j < 16; ++j) xv[j] = xp[(m0 + 32 + j) * 64];
    }
    COMP(xn, m0 + 16);
  }

  // ---------- cross-wave K-reduce ----------
  red[w][0][t] = a1_0 - a2_0;
  red[w][1][t] = a1_1 - a2_1;
  red[w][2][t] = a1_2 - a2_2;
  red[w][3][t] = a1_3 - a2_3;
  __syncthreads();
  const float yv =
      0.5f * (red[0][w][t] + red[1][w][t] + red[2][w][t] + red[3][w][t]);

  // ---------- band write: wave-uniform tt -> coalesced bursts ----------
  const long long rowoff = (long long)(nb + w) << 10;
  for (int tt = 0; tt < 64; ++tt) {
    if (t <= tt) {
      out[((long long)tt << 20) + rowoff + (1023 - tt) + t] = yv;
    }
  }

  // ---------- static post-gemv fill share ----------
  __builtin_amdgcn_s_setprio(0);
  const int gid = blockIdx.x * 4 + w;      // 0..1023
  fill_rows(out, 52224 + gid * 8, 8, 59776, t);
}

// ---- fallback (round-6 fused, known-passing; used only if ws too small) ----
__global__ __launch_bounds__(256) void hopf_fused_fb(
    const float* __restrict__ x_re, const float* __restrict__ x_im,
    const float* __restrict__ B_re, const float* __restrict__ B_im,
    float* __restrict__ out) {
  __shared__ float s1[64][65];
  __shared__ float s2[64][65];
  const int tid = threadIdx.x;
  if (blockIdx.x >= 256) {
    float4* out4 = (float4*)out;
    const float4 z = make_float4(0.f, 0.f, 0.f, 0.f);
    const int stride = 768 * 256;
    for (int q = (int)(blockIdx.x - 256) * 256 + tid; q < (1 << 24);
         q += stride) {
      const int t = q >> 18;
      const int u4 = q & 255;
      const int sb = t + 4 * u4 - 1023;
      if (sb <= -4) {
        out4[q] = z;
      } else if (sb < 0) {
        float* p = out + ((long long)q << 2);
        p[0] = 0.f;
        if (sb + 1 < 0) p[1] = 0.f;
        if (sb + 2 < 0) p[2] = 0.f;
      }
    }
    return;
  }
  const int t = tid & 63;
  const int ng = tid >> 6;
  const int n = blockIdx.x * 4 + ng;
  const float* p1 = B_re + n * NDIM;
  const float* p2 = B_im + n * NDIM;
  float a1 = 0.f, a2 = 0.f;
  for (int m0 = 0; m0 < NDIM; m0 += 64) {
    __syncthreads();
#pragma unroll
    for (int k = 0; k < 16; ++k) {
      const int s = tid + k * 256;
      const int tr2 = s >> 6, j = s & 63;
      s1[tr2][j] = x_re[tr2 * NDIM + m0 + j];
      s2[tr2][j] = x_im[tr2 * NDIM + m0 + j];
    }
    __syncthreads();
#pragma unroll 16
    for (int mm = 0; mm < 64; ++mm) {
      a1 = fmaf(p1[m0 + mm], s1[t][mm], a1);
      a2 = fmaf(p2[m0 + mm], s2[t][mm], a2);
    }
  }
  const float yv = 0.5f * (a1 - a2);
  const long long rowoff = (long long)(n << 10);
  for (int tt = 0; tt < 64; ++tt) {
    if (t <= tt) {
      out[((long long)tt << 20) + rowoff + (1023 - tt) + t] = yv;
    }
  }
}

extern "C" void kernel_launch(void* const* d_in, const int* in_sizes, int n_in,
                              void* d_out, int out_size, void* d_ws, size_t ws_size,
                              hipStream_t stream) {
  (void)in_sizes; (void)n_in; (void)out_size;
  const float* x_re = (const float*)d_in[0];
  const float* x_im = (const float*)d_in[1];
  const float* B_re = (const float*)d_in[4];
  const float* B_im = (const float*)d_in[5];
  float* out = (float*)d_out;

  if (ws_size >= (size_t)(NDIM * 64 * sizeof(unsigned))) {
    unsigned* xTb = (unsigned*)d_ws;   // [1024 m][64 t] packed bf16, 256 KB
    k0_transpose_fill<<<256, 256, 0, stream>>>(x_re, x_im, xTb, out);
    hopf_fused8<<<1024, 256, 0, stream>>>(xTb, B_re, B_im, out);
  } else {
    hopf_fused_fb<<<1024, 256, 0, stream>>>(x_re, x_im, B_re, B_im, out);
  }
}

// Round 16
// 44.202 us; speedup vs baseline: 2.6770x; 1.0231x over previous
//
#include <hip/hip_runtime.h>

// HopfRNNCellTheta: T=64 < UNITS=1024 -> z[:,0] stays 0 -> A unused,
// y_t = 0.5*(B@x_t). Output = REAL part only, float32[64][1024][1024].
// out[t][n][u] = ReY[s][n], s = t+u-1023, if s>=0 else 0.
//
// r16 = r15 + f16 dot2 gemv: xT packed (xr, -xi) f16x2, B staged packed
// (br, bi) f16x2 in wave-private LDS -> inner loop = ONE v_dot2_f32_f16 per
// (row,m), zero unpack. 8 rows/block (128 gemv blocks) halves xT L2 traffic
// again (64->32 MB). LDS 40 KB keeps 4 blocks/CU. f16 (10-bit mantissa)
// improves absmax vs r15's bf16.

#define NDIM 1024

typedef _Float16 half2_t __attribute__((ext_vector_type(2)));

__device__ __forceinline__ unsigned pk_f16(float a, float b) {
  return __builtin_bit_cast(unsigned, __builtin_amdgcn_cvt_pkrtz(a, b));
}
__device__ __forceinline__ half2_t bc2(unsigned u) {
  return __builtin_bit_cast(half2_t, u);
}

// zero-prefix of row r = (t,n): words [0,Z) zero, word Z comps [0,k) zero.
// Z = (1023-t)>>2 in [240,256), k = (1023-t)&3. Band cells untouched.
__device__ __forceinline__ void fill_rows(float* __restrict__ out, int rstart,
                                          int rcount, int rlimit, int lane) {
  const float4 z = make_float4(0.f, 0.f, 0.f, 0.f);
  int rend = rstart + rcount;
  if (rend > rlimit) rend = rlimit;
  for (int r = rstart; r < rend; ++r) {
    const int t = r >> 10;
    const int n = r & 1023;
    const int rem = 1023 - t;
    const int Z = rem >> 2;
    const int k = rem & 3;
    float4* rp = (float4*)out + ((long long)t << 18) + (n << 8);
    rp[lane] = z;                          // lanes 0..63  (< 240 <= Z)
    rp[lane + 64] = z;
    rp[lane + 128] = z;
    if (lane + 192 < Z) rp[lane + 192] = z;
    if (lane < k) ((float*)(rp + Z))[lane] = 0.f;
  }
}

// ---- K0: 16 transpose+pack blocks + 240 fill blocks ----
__global__ __launch_bounds__(256) void k0_transpose_fill(
    const float* __restrict__ x_re, const float* __restrict__ x_im,
    unsigned* __restrict__ xTh, float* __restrict__ out) {
  __shared__ float s1[64][65];
  __shared__ float s2[64][65];
  const int tid = threadIdx.x;
  if (blockIdx.x >= 16) {
    const int kw = (int)(blockIdx.x - 16) * 4 + (tid >> 6);  // 0..959
    fill_rows(out, 59776 + kw * 6, 6, 65536, tid & 63);
    return;
  }
  const int m0 = blockIdx.x * 64;
#pragma unroll
  for (int k = 0; k < 16; ++k) {           // coalesced reads
    const int s = tid + k * 256;
    const int tr = s >> 6, j = s & 63;
    s1[tr][j] = x_re[tr * NDIM + m0 + j];
    s2[tr][j] = x_im[tr * NDIM + m0 + j];
  }
  __syncthreads();
#pragma unroll
  for (int k = 0; k < 16; ++k) {           // coalesced writes, CF LDS reads
    const int s = tid + k * 256;
    const int ml = s >> 6, t = s & 63;
    // f16 pair (xr, -xi): dot2 with (br, bi) gives br*xr - bi*xi directly
    xTh[(m0 + ml) * 64 + t] = pk_f16(s1[t][ml], -s2[t][ml]);
  }
}

// ---- K1: fused gemv + row-structured zero-fill ----
__global__ __launch_bounds__(256) void hopf_fused9(
    const unsigned* __restrict__ xTh,
    const float* __restrict__ B_re, const float* __restrict__ B_im,
    float* __restrict__ out) {
  __shared__ unsigned bs[4][8][256];   // [wave][row][m'] packed (br,bi) f16
  __shared__ float red[4][8][64];      // [k-wave][row][t]
  const int tid = threadIdx.x;
  const int t = tid & 63;
  const int w = tid >> 6;

  if (blockIdx.x >= 128) {
    const int gfw = (int)(blockIdx.x - 128) * 4 + w;   // 0..3583
    fill_rows(out, gfw * 16, 16, 57344, t);
    return;
  }

  // ---------- gemv: block rows nb..nb+7; wave w reduces m-quarter w ----------
  __builtin_amdgcn_s_setprio(1);
  const int nb = blockIdx.x * 8;
  const int mbase = w << 8;

  // stage B[nb+r][mbase..mbase+256) packed f16 into wave-private LDS
  // (no barrier: same-wave ds_write->ds_read ordered by compiler lgkmcnt)
#pragma unroll
  for (int r = 0; r < 8; ++r) {
    const float4 re = *(const float4*)(B_re + (nb + r) * NDIM + mbase + t * 4);
    const float4 im = *(const float4*)(B_im + (nb + r) * NDIM + mbase + t * 4);
    uint4 pk;
    pk.x = pk_f16(re.x, im.x);
    pk.y = pk_f16(re.y, im.y);
    pk.z = pk_f16(re.z, im.z);
    pk.w = pk_f16(re.w, im.w);
    *(uint4*)&bs[w][r][t * 4] = pk;
  }

  float acc0 = 0.f, acc1 = 0.f, acc2 = 0.f, acc3 = 0.f;
  float acc4 = 0.f, acc5 = 0.f, acc6 = 0.f, acc7 = 0.f;
  const unsigned* xp = xTh + (mbase << 6) + t;
  unsigned xv[16], xn[16];

#define ROWDOT(R, BQ)                                                   \
  do {                                                                  \
    acc##R = __builtin_amdgcn_fdot2(bc2(BQ.x), x0, acc##R, false);      \
    acc##R = __builtin_amdgcn_fdot2(bc2(BQ.y), x1, acc##R, false);      \
    acc##R = __builtin_amdgcn_fdot2(bc2(BQ.z), x2, acc##R, false);      \
    acc##R = __builtin_amdgcn_fdot2(bc2(BQ.w), x3, acc##R, false);      \
  } while (0)

#define COMP(X, MB)                                                     \
  do {                                                                  \
    _Pragma("unroll")                                                   \
    for (int q = 0; q < 4; ++q) {                                       \
      const half2_t x0 = bc2(X[q * 4 + 0]);                             \
      const half2_t x1 = bc2(X[q * 4 + 1]);                             \
      const half2_t x2 = bc2(X[q * 4 + 2]);                             \
      const half2_t x3 = bc2(X[q * 4 + 3]);                             \
      const uint4 b0 = *(const uint4*)&bs[w][0][(MB) + q * 4];          \
      ROWDOT(0, b0);                                                    \
      const uint4 b1 = *(const uint4*)&bs[w][1][(MB) + q * 4];          \
      ROWDOT(1, b1);                                                    \
      const uint4 b2 = *(const uint4*)&bs[w][2][(MB) + q * 4];          \
      ROWDOT(2, b2);                                                    \
      const uint4 b3 = *(const uint4*)&bs[w][3][(MB) + q * 4];          \
      ROWDOT(3, b3);                                                    \
      const uint4 b4 = *(const uint4*)&bs[w][4][(MB) + q * 4];          \
      ROWDOT(4, b4);                                                    \
      const uint4 b5 = *(const uint4*)&bs[w][5][(MB) + q * 4];          \
      ROWDOT(5, b5);                                                    \
      const uint4 b6 = *(const uint4*)&bs[w][6][(MB) + q * 4];          \
      ROWDOT(6, b6);                                                    \
      const uint4 b7 = *(const uint4*)&bs[w][7][(MB) + q * 4];          \
      ROWDOT(7, b7);                                                    \
    }                                                                   \
  } while (0)

#pragma unroll
  for (int j = 0; j < 16; ++j) xv[j] = xp[j * 64];   // chunk 0 in flight

#pragma unroll 1
  for (int m0 = 0; m0 < 256; m0 += 32) {
#pragma unroll
    for (int j = 0; j < 16; ++j) xn[j] = xp[(m0 + 16 + j) * 64];
    COMP(xv, m0);
    if (m0 + 32 < 256) {
#pragma unroll
      for (int j = 0; j < 16; ++j) xv[j] = xp[(m0 + 32 + j) * 64];
    }
    COMP(xn, m0 + 16);
  }

  // ---------- cross-wave K-reduce ----------
  red[w][0][t] = acc0;
  red[w][1][t] = acc1;
  red[w][2][t] = acc2;
  red[w][3][t] = acc3;
  red[w][4][t] = acc4;
  red[w][5][t] = acc5;
  red[w][6][t] = acc6;
  red[w][7][t] = acc7;
  __syncthreads();
  // wave w owns rows nb+w and nb+w+4
  const float yv0 =
      0.5f * (red[0][w][t] + red[1][w][t] + red[2][w][t] + red[3][w][t]);
  const int w4 = w + 4;
  const float yv1 =
      0.5f * (red[0][w4][t] + red[1][w4][t] + red[2][w4][t] + red[3][w4][t]);

  // ---------- band write: wave-uniform tt -> coalesced bursts ----------
  const long long ro0 = (long long)(nb + w) << 10;
  const long long ro1 = (long long)(nb + w4) << 10;
  for (int tt = 0; tt < 64; ++tt) {
    if (t <= tt) {
      const long long po = ((long long)tt << 20) + (1023 - tt) + t;
      out[po + ro0] = yv0;
      out[po + ro1] = yv1;
    }
  }

  // ---------- static post-gemv fill share ----------
  __builtin_amdgcn_s_setprio(0);
  const int gid = blockIdx.x * 4 + w;      // 0..511
  fill_rows(out, 57344 + gid * 5, 5, 59776, t);
}

// ---- fallback (round-6 fused, known-passing; used only if ws too small) ----
__global__ __launch_bounds__(256) void hopf_fused_fb(
    const float* __restrict__ x_re, const float* __restrict__ x_im,
    const float* __restrict__ B_re, const float* __restrict__ B_im,
    float* __restrict__ out) {
  __shared__ float s1[64][65];
  __shared__ float s2[64][65];
  const int tid = threadIdx.x;
  if (blockIdx.x >= 256) {
    float4* out4 = (float4*)out;
    const float4 z = make_float4(0.f, 0.f, 0.f, 0.f);
    const int stride = 768 * 256;
    for (int q = (int)(blockIdx.x - 256) * 256 + tid; q < (1 << 24);
         q += stride) {
      const int t = q >> 18;
      const int u4 = q & 255;
      const int sb = t + 4 * u4 - 1023;
      if (sb <= -4) {
        out4[q] = z;
      } else if (sb < 0) {
        float* p = out + ((long long)q << 2);
        p[0] = 0.f;
        if (sb + 1 < 0) p[1] = 0.f;
        if (sb + 2 < 0) p[2] = 0.f;
      }
    }
    return;
  }
  const int t = tid & 63;
  const int ng = tid >> 6;
  const int n = blockIdx.x * 4 + ng;
  const float* p1 = B_re + n * NDIM;
  const float* p2 = B_im + n * NDIM;
  float a1 = 0.f, a2 = 0.f;
  for (int m0 = 0; m0 < NDIM; m0 += 64) {
    __syncthreads();
#pragma unroll
    for (int k = 0; k < 16; ++k) {
      const int s = tid + k * 256;
      const int tr2 = s >> 6, j = s & 63;
      s1[tr2][j] = x_re[tr2 * NDIM + m0 + j];
      s2[tr2][j] = x_im[tr2 * NDIM + m0 + j];
    }
    __syncthreads();
#pragma unroll 16
    for (int mm = 0; mm < 64; ++mm) {
      a1 = fmaf(p1[m0 + mm], s1[t][mm], a1);
      a2 = fmaf(p2[m0 + mm], s2[t][mm], a2);
    }
  }
  const float yv = 0.5f * (a1 - a2);
  const long long rowoff = (long long)(n << 10);
  for (int tt = 0; tt < 64; ++tt) {
    if (t <= tt) {
      out[((long long)tt << 20) + rowoff + (1023 - tt) + t] = yv;
    }
  }
}

extern "C" void kernel_launch(void* const* d_in, const int* in_sizes, int n_in,
                              void* d_out, int out_size, void* d_ws, size_t ws_size,
                              hipStream_t stream) {
  (void)in_sizes; (void)n_in; (void)out_size;
  const float* x_re = (const float*)d_in[0];
  const float* x_im = (const float*)d_in[1];
  const float* B_re = (const float*)d_in[4];
  const float* B_im = (const float*)d_in[5];
  float* out = (float*)d_out;

  if (ws_size >= (size_t)(NDIM * 64 * sizeof(unsigned))) {
    unsigned* xTh = (unsigned*)d_ws;   // [1024 m][64 t] packed f16 (xr,-xi)
    k0_transpose_fill<<<256, 256, 0, stream>>>(x_re, x_im, xTh, out);
    hopf_fused9<<<1024, 256, 0, stream>>>(xTh, B_re, B_im, out);
  } else {
    hopf_fused_fb<<<1024, 256, 0, stream>>>(x_re, x_im, B_re, B_im, out);
  }
}